// Round 3
// baseline (41.296 us; speedup 1.0000x reference)
//
#include <hip/hip_runtime.h>

#define BUCKET_MASK ((1u << 21) - 1u)

typedef float f4 __attribute__((ext_vector_type(4)));

// Layout: blockIdx.y = level (0 or 1). Each point is handled by 8 lanes
// (one float4 chunk of the 32-float feature row each). 256 threads/block =
// 32 points. A wave (64 lanes) = 8 points, all on the SAME level -> every
// gather instruction touches 8 cache lines of one table.
__global__ __launch_bounds__(256) void voxel_hash_kernel(
    const float* __restrict__ pts,
    const float* __restrict__ feats0,
    const float* __restrict__ feats1,
    float* __restrict__ out,
    int npts)
{
    int level = blockIdx.y;
    int t = blockIdx.x * 256 + threadIdx.x;
    int n     = t >> 3;          // point index
    int chunk = t & 7;           // float4 index within the 32-float row
    if (n >= npts) return;

    const float res = level ? 0.12f : 0.24f;
    const float* __restrict__ feats = level ? feats1 : feats0;

    // read-once point coords; nontemporal to avoid L2 pollution
    float px = __builtin_nontemporal_load(pts + n * 3 + 0);
    float py = __builtin_nontemporal_load(pts + n * 3 + 1);
    float pz = __builtin_nontemporal_load(pts + n * 3 + 2);

    // IEEE f32 divide to exactly match jnp (pts / float32(res))
    float qx = px / res, qy = py / res, qz = pz / res;
    float bx = floorf(qx), by = floorf(qy), bz = floorf(qz);
    float fx = qx - bx, fy = qy - by, fz = qz - bz;

    int ix = (int)bx, iy = (int)by, iz = (int)bz;

    // Hash in uint32: low 21 bits of the mod-2^32 sum == int64 floored mod 2^21.
    unsigned hx0 = (unsigned)ix * 73856093u;
    unsigned hy0 = (unsigned)iy * 19349669u;
    unsigned hz0 = (unsigned)iz * 83492791u;
    unsigned hx1 = hx0 + 73856093u;
    unsigned hy1 = hy0 + 19349669u;
    unsigned hz1 = hz0 + 83492791u;

    float gx = 1.0f - fx, gy = 1.0f - fy, gz = 1.0f - fz;

    f4 acc = (f4)(0.0f);

    #pragma unroll
    for (int c = 0; c < 8; ++c) {
        unsigned h = ((c & 1) ? hx1 : hx0)
                   + ((c & 2) ? hy1 : hy0)
                   + ((c & 4) ? hz1 : hz0);
        unsigned vid = h & BUCKET_MASK;
        float w = ((c & 1) ? fx : gx) * ((c & 2) ? fy : gy) * ((c & 4) ? fz : gz);

        const f4 f = *reinterpret_cast<const f4*>(
            feats + (size_t)vid * 32u + (unsigned)chunk * 4u);
        acc += w * f;
    }

    // streaming output, never re-read: keep it out of L2
    f4* dst = reinterpret_cast<f4*>(
        out + (size_t)n * 64u + (unsigned)level * 32u + (unsigned)chunk * 4u);
    __builtin_nontemporal_store(acc, dst);
}

extern "C" void kernel_launch(void* const* d_in, const int* in_sizes, int n_in,
                              void* d_out, int out_size, void* d_ws, size_t ws_size,
                              hipStream_t stream) {
    const float* pts = (const float*)d_in[0];
    const float* f0  = (const float*)d_in[1];
    const float* f1  = (const float*)d_in[2];
    float* out = (float*)d_out;

    int npts = in_sizes[0] / 3;               // 262144
    long long threads = (long long)npts * 8;  // 8 lanes per point per level
    int gx = (int)((threads + 255) / 256);
    dim3 grid(gx, 2, 1);                      // y = level

    voxel_hash_kernel<<<grid, 256, 0, stream>>>(pts, f0, f1, out, npts);
}